// Round 1
// baseline (506.756 us; speedup 1.0000x reference)
//
#include <hip/hip_runtime.h>
#include <math.h>

#define BB 8
#define HH 128
#define WW 128
#define DD 512
// region geometry: region_h = 32, stride 24, 4 regions, all 32x32 (1024 px)

__device__ __forceinline__ float4 f4z() { return make_float4(0.f, 0.f, 0.f, 0.f); }
__device__ __forceinline__ float4 f4add(float4 a, float4 b) {
    return make_float4(a.x + b.x, a.y + b.y, a.z + b.z, a.w + b.w);
}
__device__ __forceinline__ float4 f4fma(float s, float4 a, float4 acc) {
    return make_float4(fmaf(s, a.x, acc.x), fmaf(s, a.y, acc.y),
                       fmaf(s, a.z, acc.z), fmaf(s, a.w, acc.w));
}
__device__ __forceinline__ float4 f4scale(float4 a, float s) {
    return make_float4(a.x * s, a.y * s, a.z * s, a.w * s);
}

// ---------------------------------------------------------------------------
// k1: per (b,h) row, compute 4 overlapping column-strip sums + row total.
// grid = B*H blocks, 128 threads, each thread owns a float4 of D.
// ---------------------------------------------------------------------------
__global__ __launch_bounds__(128) void k1_rowsums(const float* __restrict__ f,
                                                  float* __restrict__ rowpart,
                                                  float* __restrict__ rowtot) {
    const int bh = blockIdx.x;            // b*H + h
    const int d4 = threadIdx.x * 4;       // element index in D
    const float4* p = (const float4*)(f + (size_t)bh * WW * DD + d4);
    // p[w * (DD/4)] is the float4 at (b,h,w,d4)

    float4 tot = f4z(), r0 = f4z(), r1 = f4z(), r2 = f4z(), r3 = f4z();

#define SEG(W0, W1, STMT)                                  \
    _Pragma("unroll 4")                                    \
    for (int w = (W0); w < (W1); ++w) {                    \
        float4 v = p[(size_t)w * (DD / 4)];                \
        tot = f4add(tot, v);                               \
        STMT                                               \
    }
    // strip j covers w in [24j, 24j+32)
    SEG(0, 24,   r0 = f4add(r0, v);)
    SEG(24, 32,  r0 = f4add(r0, v); r1 = f4add(r1, v);)
    SEG(32, 48,  r1 = f4add(r1, v);)
    SEG(48, 56,  r1 = f4add(r1, v); r2 = f4add(r2, v);)
    SEG(56, 72,  r2 = f4add(r2, v);)
    SEG(72, 80,  r2 = f4add(r2, v); r3 = f4add(r3, v);)
    SEG(80, 104, r3 = f4add(r3, v);)
    SEG(104, 128, )
#undef SEG

    float4* rp = (float4*)(rowpart + ((size_t)bh * 4) * DD + d4);
    rp[0 * (DD / 4)] = r0;
    rp[1 * (DD / 4)] = r1;
    rp[2 * (DD / 4)] = r2;
    rp[3 * (DD / 4)] = r3;
    *(float4*)(rowtot + (size_t)bh * DD + d4) = tot;
}

// ---------------------------------------------------------------------------
// k2: reduce rows into region means (/1024) and global mean (/16384).
// blocks 0..B*16-1: (b, r=i*4+j) region mean. blocks B*16..B*16+B-1: global.
// ---------------------------------------------------------------------------
__global__ __launch_bounds__(128) void k2_reduce(const float* __restrict__ rowpart,
                                                 const float* __restrict__ rowtot,
                                                 float* __restrict__ means,
                                                 float* __restrict__ gmean) {
    const int blk = blockIdx.x;
    const int d4 = threadIdx.x * 4;
    if (blk < BB * 16) {
        const int b = blk >> 4;
        const int r = blk & 15;
        const int i = r >> 2;
        const int j = r & 3;
        const int h0 = i * 24;
        float4 s = f4z();
#pragma unroll 4
        for (int hh = 0; hh < 32; ++hh) {
            const int bh = b * HH + h0 + hh;
            s = f4add(s, *(const float4*)(rowpart + ((size_t)bh * 4 + j) * DD + d4));
        }
        s = f4scale(s, 1.0f / 1024.0f);
        *(float4*)(means + ((size_t)b * 16 + r) * DD + d4) = s;
    } else {
        const int b = blk - BB * 16;
        float4 s = f4z();
#pragma unroll 4
        for (int h = 0; h < HH; ++h) {
            s = f4add(s, *(const float4*)(rowtot + ((size_t)(b * HH + h)) * DD + d4));
        }
        s = f4scale(s, 1.0f / (float)(HH * WW));
        *(float4*)(gmean + (size_t)b * DD + d4) = s;
    }
}

// ---------------------------------------------------------------------------
// k3: per-pixel output. grid = B*H blocks, 128 threads (float4 over D).
// out = f + 0.4*g + 0.6 * (sum_j ww[j,w]*cs[j]) / (Hs*Ws + 1e-8)
// where cs[j] = sum_i hw[i,h]*means[b,i*4+j,:]
// ---------------------------------------------------------------------------
__global__ __launch_bounds__(128) void k3_output(const float* __restrict__ f,
                                                 const float* __restrict__ means,
                                                 const float* __restrict__ gmean,
                                                 float* __restrict__ out) {
    const int bh = blockIdx.x;
    const int b = bh / HH;
    const int h = bh % HH;
    const int tid = threadIdx.x;
    const int d4 = tid * 4;

    __shared__ float4 sww[WW];   // (ww0,ww1,ww2,ww3) per w
    __shared__ float sinv[WW];   // 1/(Hs*Ws + 1e-8) per w

    // h weights (uniform across the block)
    const float hc = (3.0f / 127.0f) * (float)h;
    float hwv[4];
    float Hs = 0.f;
#pragma unroll
    for (int i = 0; i < 4; ++i) {
        const float t = (hc - (float)i) * 0.25f;
        hwv[i] = __expf(-2.0f * t * t);
        Hs += hwv[i];
    }

    // w tables: one thread per w (blockDim == W == 128)
    {
        const float wc = (3.0f / 127.0f) * (float)tid;
        float wv[4];
        float Ws = 0.f;
#pragma unroll
        for (int j = 0; j < 4; ++j) {
            const float t = (wc - (float)j) * 0.25f;
            wv[j] = __expf(-2.0f * t * t);
            Ws += wv[j];
        }
        sww[tid] = make_float4(wv[0], wv[1], wv[2], wv[3]);
        sinv[tid] = 1.0f / (Hs * Ws + 1e-8f);
    }
    __syncthreads();

    // per-thread column-combined means: cs[j] = sum_i hw[i]*m[b, i*4+j, d4..d4+3]
    float4 cs0 = f4z(), cs1 = f4z(), cs2 = f4z(), cs3 = f4z();
#pragma unroll
    for (int i = 0; i < 4; ++i) {
        const float hwi = hwv[i];
        const float4* mrow = (const float4*)(means + ((size_t)b * 16 + i * 4) * DD + d4);
        cs0 = f4fma(hwi, mrow[0 * (DD / 4)], cs0);
        cs1 = f4fma(hwi, mrow[1 * (DD / 4)], cs1);
        cs2 = f4fma(hwi, mrow[2 * (DD / 4)], cs2);
        cs3 = f4fma(hwi, mrow[3 * (DD / 4)], cs3);
    }
    const float4 g = *(const float4*)(gmean + (size_t)b * DD + d4);
    const float4 gterm = f4scale(g, 0.4f);  // (1-rw)*global, rw=0.6

    const float4* fp = (const float4*)(f + (size_t)bh * WW * DD + d4);
    float4* op = (float4*)(out + (size_t)bh * WW * DD + d4);

#pragma unroll 4
    for (int w = 0; w < WW; ++w) {
        const float4 v = fp[(size_t)w * (DD / 4)];
        const float4 wwv = sww[w];
        const float inv = sinv[w] * 0.6f;  // fold rw into the normalizer
        float4 o;
        o.x = v.x + gterm.x + (cs0.x * wwv.x + cs1.x * wwv.y + cs2.x * wwv.z + cs3.x * wwv.w) * inv;
        o.y = v.y + gterm.y + (cs0.y * wwv.x + cs1.y * wwv.y + cs2.y * wwv.z + cs3.y * wwv.w) * inv;
        o.z = v.z + gterm.z + (cs0.z * wwv.x + cs1.z * wwv.y + cs2.z * wwv.z + cs3.z * wwv.w) * inv;
        o.w = v.w + gterm.w + (cs0.w * wwv.x + cs1.w * wwv.y + cs2.w * wwv.z + cs3.w * wwv.w) * inv;
        op[(size_t)w * (DD / 4)] = o;
    }
}

extern "C" void kernel_launch(void* const* d_in, const int* in_sizes, int n_in,
                              void* d_out, int out_size, void* d_ws, size_t ws_size,
                              hipStream_t stream) {
    const float* f = (const float*)d_in[0];
    float* out = (float*)d_out;

    // workspace layout (floats): rowpart | rowtot | means | gmean  (~10.4 MiB)
    float* ws = (float*)d_ws;
    float* rowpart = ws;                                   // B*H*4*D
    float* rowtot = rowpart + (size_t)BB * HH * 4 * DD;    // B*H*D
    float* means = rowtot + (size_t)BB * HH * DD;          // B*16*D
    float* gmean = means + (size_t)BB * 16 * DD;           // B*D

    k1_rowsums<<<BB * HH, 128, 0, stream>>>(f, rowpart, rowtot);
    k2_reduce<<<BB * 16 + BB, 128, 0, stream>>>(rowpart, rowtot, means, gmean);
    k3_output<<<BB * HH, 128, 0, stream>>>(f, means, gmean, out);
}

// Round 2
// 496.029 us; speedup vs baseline: 1.0216x; 1.0216x over previous
//
#include <hip/hip_runtime.h>
#include <math.h>

#define BB 8
#define HH 128
#define WW 128
#define DD 512
// region geometry: region_h = 32, stride 24, 4 regions, all 32x32 (1024 px)

__device__ __forceinline__ float4 f4z() { return make_float4(0.f, 0.f, 0.f, 0.f); }
__device__ __forceinline__ float4 f4add(float4 a, float4 b) {
    return make_float4(a.x + b.x, a.y + b.y, a.z + b.z, a.w + b.w);
}
__device__ __forceinline__ float4 f4fma(float s, float4 a, float4 acc) {
    return make_float4(fmaf(s, a.x, acc.x), fmaf(s, a.y, acc.y),
                       fmaf(s, a.z, acc.z), fmaf(s, a.w, acc.w));
}
__device__ __forceinline__ float4 f4scale(float4 a, float s) {
    return make_float4(a.x * s, a.y * s, a.z * s, a.w * s);
}

// ---------------------------------------------------------------------------
// k1: per (b,h) row, compute 4 overlapping column-strip sums + row total.
// grid = B*H blocks, 512 threads = 8 waves (32 waves/CU at 4 blocks/CU).
// Thread layout: dt = tid&127 owns float4 d-slice, g = tid>>7 owns w mod 4.
// Each iteration `it` the block reads the contiguous 8 KiB chunk w=[4it,4it+4).
// Strip boundaries (0,24,32,48,56,72,80,104,128) are multiples of 8, so strip
// membership is uniform within each 4-wide chunk -> branchless segments in it.
// ---------------------------------------------------------------------------
__global__ __launch_bounds__(512) void k1_rowsums(const float* __restrict__ f,
                                                  float* __restrict__ rowpart,
                                                  float* __restrict__ rowtot) {
    const int bh = blockIdx.x;            // b*H + h
    const int tid = threadIdx.x;
    const int dt = tid & 127;             // d float4 index
    const int g = tid >> 7;               // w-group 0..3
    const int d4 = dt * 4;

    // element (w = 4*it + g, d4): p[it * 4 * (DD/4)]
    const float4* p = (const float4*)(f + (size_t)bh * WW * DD) + (size_t)g * (DD / 4) + dt;

    float4 tot = f4z(), r0 = f4z(), r1 = f4z(), r2 = f4z(), r3 = f4z();

#define SEG(I0, I1, STMT)                                  \
    _Pragma("unroll")                                      \
    for (int it = (I0); it < (I1); ++it) {                 \
        float4 v = p[(size_t)it * 4 * (DD / 4)];           \
        tot = f4add(tot, v);                               \
        STMT                                               \
    }
    // strip j covers w in [24j, 24j+32); it = w/4
    SEG(0, 6,   r0 = f4add(r0, v);)
    SEG(6, 8,   r0 = f4add(r0, v); r1 = f4add(r1, v);)
    SEG(8, 12,  r1 = f4add(r1, v);)
    SEG(12, 14, r1 = f4add(r1, v); r2 = f4add(r2, v);)
    SEG(14, 18, r2 = f4add(r2, v);)
    SEG(18, 20, r2 = f4add(r2, v); r3 = f4add(r3, v);)
    SEG(20, 26, r3 = f4add(r3, v);)
    SEG(26, 32, )
#undef SEG

    // merge the 4 w-groups through LDS (group 0 accumulates groups 1..3)
    __shared__ float4 lds[3][5][128];
    if (g > 0) {
        lds[g - 1][0][dt] = r0;
        lds[g - 1][1][dt] = r1;
        lds[g - 1][2][dt] = r2;
        lds[g - 1][3][dt] = r3;
        lds[g - 1][4][dt] = tot;
    }
    __syncthreads();
    if (g == 0) {
#pragma unroll
        for (int gg = 0; gg < 3; ++gg) {
            r0 = f4add(r0, lds[gg][0][dt]);
            r1 = f4add(r1, lds[gg][1][dt]);
            r2 = f4add(r2, lds[gg][2][dt]);
            r3 = f4add(r3, lds[gg][3][dt]);
            tot = f4add(tot, lds[gg][4][dt]);
        }
        float4* rp = (float4*)(rowpart + ((size_t)bh * 4) * DD + d4);
        rp[0 * (DD / 4)] = r0;
        rp[1 * (DD / 4)] = r1;
        rp[2 * (DD / 4)] = r2;
        rp[3 * (DD / 4)] = r3;
        *(float4*)(rowtot + (size_t)bh * DD + d4) = tot;
    }
}

// ---------------------------------------------------------------------------
// k2: reduce rows into region means (/1024) and global mean (/16384).
// blocks 0..B*16-1: (b, r=i*4+j) region mean. blocks B*16..B*16+B-1: global.
// ---------------------------------------------------------------------------
__global__ __launch_bounds__(128) void k2_reduce(const float* __restrict__ rowpart,
                                                 const float* __restrict__ rowtot,
                                                 float* __restrict__ means,
                                                 float* __restrict__ gmean) {
    const int blk = blockIdx.x;
    const int d4 = threadIdx.x * 4;
    if (blk < BB * 16) {
        const int b = blk >> 4;
        const int r = blk & 15;
        const int i = r >> 2;
        const int j = r & 3;
        const int h0 = i * 24;
        float4 s = f4z();
#pragma unroll 8
        for (int hh = 0; hh < 32; ++hh) {
            const int bh = b * HH + h0 + hh;
            s = f4add(s, *(const float4*)(rowpart + ((size_t)bh * 4 + j) * DD + d4));
        }
        s = f4scale(s, 1.0f / 1024.0f);
        *(float4*)(means + ((size_t)b * 16 + r) * DD + d4) = s;
    } else {
        const int b = blk - BB * 16;
        float4 s = f4z();
#pragma unroll 8
        for (int h = 0; h < HH; ++h) {
            s = f4add(s, *(const float4*)(rowtot + (size_t)(b * HH + h) * DD + d4));
        }
        s = f4scale(s, 1.0f / (float)(HH * WW));
        *(float4*)(gmean + (size_t)b * DD + d4) = s;
    }
}

// ---------------------------------------------------------------------------
// k3: per-pixel output. grid = B*H blocks, 512 threads (8 waves), same
// (dt, g) layout as k1. out = f + 0.4*g + 0.6*(sum_j ww[j,w]*cs[j])/(Hs*Ws+1e-8)
// where cs[j] = sum_i hw[i,h]*means[b,i*4+j,:]  (per-thread, 16 FMAs once).
// ---------------------------------------------------------------------------
__global__ __launch_bounds__(512) void k3_output(const float* __restrict__ f,
                                                 const float* __restrict__ means,
                                                 const float* __restrict__ gmean,
                                                 float* __restrict__ out) {
    const int bh = blockIdx.x;
    const int b = bh / HH;
    const int h = bh % HH;
    const int tid = threadIdx.x;
    const int dt = tid & 127;
    const int g = tid >> 7;
    const int d4 = dt * 4;

    __shared__ float4 sww[WW];   // (ww0,ww1,ww2,ww3) per w
    __shared__ float sinv[WW];   // 0.6/(Hs*Ws + 1e-8) per w

    // h weights (uniform across the block)
    const float hc = (3.0f / 127.0f) * (float)h;
    float hwv[4];
    float Hs = 0.f;
#pragma unroll
    for (int i = 0; i < 4; ++i) {
        const float t = (hc - (float)i) * 0.25f;
        hwv[i] = __expf(-2.0f * t * t);
        Hs += hwv[i];
    }

    // w tables: threads 0..127 fill one w each
    if (tid < WW) {
        const float wc = (3.0f / 127.0f) * (float)tid;
        float wv[4];
        float Ws = 0.f;
#pragma unroll
        for (int j = 0; j < 4; ++j) {
            const float t = (wc - (float)j) * 0.25f;
            wv[j] = __expf(-2.0f * t * t);
            Ws += wv[j];
        }
        sww[tid] = make_float4(wv[0], wv[1], wv[2], wv[3]);
        sinv[tid] = 0.6f / (Hs * Ws + 1e-8f);
    }
    __syncthreads();

    // per-thread column-combined means: cs[j] = sum_i hw[i]*m[b, i*4+j, d4..d4+3]
    float4 cs0 = f4z(), cs1 = f4z(), cs2 = f4z(), cs3 = f4z();
#pragma unroll
    for (int i = 0; i < 4; ++i) {
        const float hwi = hwv[i];
        const float4* mrow = (const float4*)(means + ((size_t)b * 16 + i * 4) * DD + d4);
        cs0 = f4fma(hwi, mrow[0 * (DD / 4)], cs0);
        cs1 = f4fma(hwi, mrow[1 * (DD / 4)], cs1);
        cs2 = f4fma(hwi, mrow[2 * (DD / 4)], cs2);
        cs3 = f4fma(hwi, mrow[3 * (DD / 4)], cs3);
    }
    const float4 gv = *(const float4*)(gmean + (size_t)b * DD + d4);
    const float4 gterm = f4scale(gv, 0.4f);  // (1-rw)*global, rw=0.6

    const float4* fp = (const float4*)(f + (size_t)bh * WW * DD) + (size_t)g * (DD / 4) + dt;
    float4* op = (float4*)(out + (size_t)bh * WW * DD) + (size_t)g * (DD / 4) + dt;

#pragma unroll 8
    for (int it = 0; it < 32; ++it) {
        const int w = it * 4 + g;                 // wave-uniform
        const float4 v = fp[(size_t)it * 4 * (DD / 4)];
        const float4 wwv = sww[w];                // LDS broadcast
        const float inv = sinv[w];
        float4 o;
        o.x = v.x + gterm.x + (cs0.x * wwv.x + cs1.x * wwv.y + cs2.x * wwv.z + cs3.x * wwv.w) * inv;
        o.y = v.y + gterm.y + (cs0.y * wwv.x + cs1.y * wwv.y + cs2.y * wwv.z + cs3.y * wwv.w) * inv;
        o.z = v.z + gterm.z + (cs0.z * wwv.x + cs1.z * wwv.y + cs2.z * wwv.z + cs3.z * wwv.w) * inv;
        o.w = v.w + gterm.w + (cs0.w * wwv.x + cs1.w * wwv.y + cs2.w * wwv.z + cs3.w * wwv.w) * inv;
        op[(size_t)it * 4 * (DD / 4)] = o;
    }
}

extern "C" void kernel_launch(void* const* d_in, const int* in_sizes, int n_in,
                              void* d_out, int out_size, void* d_ws, size_t ws_size,
                              hipStream_t stream) {
    const float* f = (const float*)d_in[0];
    float* out = (float*)d_out;

    // workspace layout (floats): rowpart | rowtot | means | gmean  (~10.4 MiB)
    float* ws = (float*)d_ws;
    float* rowpart = ws;                                   // B*H*4*D
    float* rowtot = rowpart + (size_t)BB * HH * 4 * DD;    // B*H*D
    float* means = rowtot + (size_t)BB * HH * DD;          // B*16*D
    float* gmean = means + (size_t)BB * 16 * DD;           // B*D

    k1_rowsums<<<BB * HH, 512, 0, stream>>>(f, rowpart, rowtot);
    k2_reduce<<<BB * 16 + BB, 128, 0, stream>>>(rowpart, rowtot, means, gmean);
    k3_output<<<BB * HH, 512, 0, stream>>>(f, means, gmean, out);
}